// Round 1
// baseline (80.368 us; speedup 1.0000x reference)
//
#include <hip/hip_runtime.h>

// C4Transformer: per-element opcode-routed expert compute.
// Inputs (setup_inputs order): a f32[N], b f32[N], log_keys f32[161],
// recip_values f32[161], opcode i32[N].  Output f32[N].
//
// Gate analysis: eq_gate is one-hot to ~2e-9; leakage * max|result| (2^31)
// ~= 4.3, threshold is 4.3e7 -> compute only the selected expert.

static constexpr int BLOCK = 256;

__device__ __forceinline__ float siluf(float x) {
    // x * sigmoid(x); saturates correctly: x->-inf gives x*0=-0, x->+inf gives x.
    return x / (1.0f + __expf(-x));
}
__device__ __forceinline__ float sharp_gatef(float x) {
    float t = x * 20.0f;
    return (siluf(t + 10.0f) - siluf(t - 10.0f)) * 0.05f;
}
__device__ __forceinline__ float eq_gatef(float d) {
    return sharp_gatef(d + 0.5f) * sharp_gatef(0.5f - d);
}

__device__ __forceinline__ float compute_one(float a, float b, int op,
                                             const float* __restrict__ recip_tbl) {
    float out = 0.0f;
    if (op >= 14 && op <= 29) {
        if (op <= 16 || op == 23 || op == 24) {
            // int-domain experts: OR, XOR, AND, SHL, SHR (bit-exact, numpy semantics)
            int ai = (int)a, bi = (int)b;
            int r;
            switch (op) {
                case 14: r = ai | bi; break;
                case 15: r = ai ^ bi; break;
                case 16: r = ai & bi; break;
                case 23: { int sh = bi < 0 ? 0 : (bi > 31 ? 31 : bi);
                           r = (int)(((unsigned)ai) << sh); } break;
                default: { int sh = bi < 0 ? 0 : (bi > 31 ? 31 : bi);
                           r = ai >> sh; } break;
            }
            out = (float)r;
        } else if (op >= 17 && op <= 22) {
            // comparison experts via sharp gates
            float d = a - b;
            switch (op) {
                case 17: out = eq_gatef(d); break;
                case 18: out = 1.0f - eq_gatef(d); break;
                case 19: out = sharp_gatef(-d - 0.5f); break;  // lt
                case 20: out = sharp_gatef(d - 0.5f);  break;  // gt
                case 21: out = sharp_gatef(-d + 0.5f); break;  // le
                default: out = sharp_gatef(d + 0.5f);  break;  // ge
            }
        } else if (op == 25) { out = a + b; }
        else if (op == 26) { out = a - b; }
        else if (op == 27) { out = a * b; }
        else {
            // op 28 (div) / 29 (mod): softmax attention over log-table.
            // Full 161-way softmax decays e^{-6.25}/step -> +-3 window is
            // ~1e-8-exact relative; stabilized by in-window min distance.
            float dv = 0.0f;
            if (b > 0.0f) {
                float logb = __log2f(b);
                int i0 = (int)floorf(logb * 8.0f + 0.5f);
                i0 = i0 < 0 ? 0 : (i0 > 160 ? 160 : i0);
                int lo = i0 - 3 < 0 ? 0 : i0 - 3;
                int hi = i0 + 3 > 160 ? 160 : i0 + 3;
                float dmin = fabsf((float)i0 * 0.125f - logb);
                float wsum = 0.0f, rsum = 0.0f;
                for (int k = lo; k <= hi; ++k) {
                    float dk = fabsf((float)k * 0.125f - logb);
                    float w = __expf(-50.0f * (dk - dmin));
                    wsum += w;
                    rsum += w * recip_tbl[k];
                }
                dv = floorf(a * (rsum / wsum));
            }
            if (op == 28) out = dv;
            else out = (b == 0.0f) ? 0.0f : (a - dv * b);
        }
    }
    return out;
}

__global__ __launch_bounds__(BLOCK) void c4_kernel(
        const float* __restrict__ A, const float* __restrict__ B,
        const int* __restrict__ OP, const float* __restrict__ recip_tbl,
        float* __restrict__ OUT, int n4, int n) {
    int i = blockIdx.x * BLOCK + threadIdx.x;
    if (i < n4) {
        float4 a4 = reinterpret_cast<const float4*>(A)[i];
        float4 b4 = reinterpret_cast<const float4*>(B)[i];
        int4   o4 = reinterpret_cast<const int4*>(OP)[i];
        float4 r;
        r.x = compute_one(a4.x, b4.x, o4.x, recip_tbl);
        r.y = compute_one(a4.y, b4.y, o4.y, recip_tbl);
        r.z = compute_one(a4.z, b4.z, o4.z, recip_tbl);
        r.w = compute_one(a4.w, b4.w, o4.w, recip_tbl);
        reinterpret_cast<float4*>(OUT)[i] = r;
    }
    // scalar tail (n % 4 != 0), handled by thread 0 of block 0
    if (i == 0) {
        for (int j = n4 * 4; j < n; ++j)
            OUT[j] = compute_one(A[j], B[j], OP[j], recip_tbl);
    }
}

extern "C" void kernel_launch(void* const* d_in, const int* in_sizes, int n_in,
                              void* d_out, int out_size, void* d_ws, size_t ws_size,
                              hipStream_t stream) {
    const float* A     = (const float*)d_in[0];
    const float* B     = (const float*)d_in[1];
    const float* recip = (const float*)d_in[3];
    const int*   OP    = (const int*)d_in[4];
    float* OUT = (float*)d_out;
    int n  = in_sizes[0];
    int n4 = n / 4;
    int blocks = (n4 + BLOCK - 1) / BLOCK;
    if (blocks < 1) blocks = 1;
    c4_kernel<<<blocks, BLOCK, 0, stream>>>(A, B, OP, recip, OUT, n4, n);
}

// Round 2
// 72.938 us; speedup vs baseline: 1.1019x; 1.1019x over previous
//
#include <hip/hip_runtime.h>

// C4Transformer: per-element opcode-routed expert compute, fully branchless.
// Inputs: a f32[N], b f32[N], log_keys f32[161], recip_values f32[161],
// opcode i32[N].  Output f32[N].
//
// R1 -> R2: random opcodes make every wave contain every op class; the R1
// switch-based kernel serially executed ~25-30 transcendentals/element under
// exec-masking. Branchless rewrite: 1 exp for all 6 comparisons (shared
// e^{-t} with e^{+-20} constant scaling + sharp_gate(-x)=1-sharp_gate(x)
// identity), 3-term softmax window for div/mod, cndmask select chain.

static constexpr int BLOCK = 256;

__device__ __forceinline__ float compute_one(float a, float b, int op,
                                             const float* __restrict__ recip_tbl) {
    // ---- int-domain experts (bit-exact numpy semantics) ----
    int ai = (int)a, bi = (int)b;
    int sh = bi < 0 ? 0 : (bi > 31 ? 31 : bi);
    float fOr  = (float)(ai | bi);
    float fXor = (float)(ai ^ bi);
    float fAnd = (float)(ai & bi);
    float fShl = (float)((int)(((unsigned)ai) << sh));
    float fShr = (float)(ai >> sh);

    // ---- comparison experts: one exp covers all six ----
    // silu(x) = x * sigmoid(x);  ge = sharp_gate(d+0.5) = (silu(t+20)-silu(t))/20
    // gt = sharp_gate(d-0.5) = (silu(t)-silu(t-20))/20, t = 20d.
    // sharp_gate(-x) = 1 - sharp_gate(x)  =>  lt = 1-ge, le = 1-gt, eq = ge*le.
    const float EM20 = 2.0611536e-9f;   // e^-20
    const float EP20 = 4.8516520e+8f;   // e^+20
    float d = a - b;
    float t = 20.0f * d;
    float E = __expf(-t);               // e^{-t}; inf/0 saturate correctly
    float sp = (t + 20.0f) / (1.0f + E * EM20);  // silu(t+20)
    float s0 = t          / (1.0f + E);          // silu(t)
    float sm = (t - 20.0f) / (1.0f + E * EP20);  // silu(t-20)
    float ge = (sp - s0) * 0.05f;
    float gt = (s0 - sm) * 0.05f;
    float lt = 1.0f - ge;
    float le = 1.0f - gt;
    float eq = ge * le;
    float ne = 1.0f - eq;

    // ---- div/mod: 3-term softmax window over the log table ----
    // b<=0 paths produce NaN/garbage here and are selected away below.
    float logb = __log2f(b);                       // NaN for b<0, -inf for b==0
    float fi0 = floorf(logb * 8.0f + 0.5f);
    fi0 = fminf(fmaxf(fi0, 0.0f), 160.0f);         // -inf -> 0; NaN handled by cvt
    int i0 = (int)fi0;                             // cvt(NaN) -> 0 on AMD
    i0 = i0 < 0 ? 0 : (i0 > 160 ? 160 : i0);       // belt and braces for table idx
    float d0 = fabsf((float)i0 * 0.125f - logb);
    float wsum = 0.0f, rsum = 0.0f;
#pragma unroll
    for (int j = -1; j <= 1; ++j) {
        int k = i0 + j;
        k = k < 0 ? 0 : (k > 160 ? 160 : k);
        float dk = fabsf((float)k * 0.125f - logb);
        float w = __expf(-50.0f * (dk - d0));
        wsum += w;
        rsum += w * recip_tbl[k];
    }
    float dvraw = floorf(a * (rsum / wsum));
    float dv  = (b > 0.0f) ? dvraw : 0.0f;
    float mod = (b == 0.0f) ? 0.0f : (a - dv * b);

    // ---- branchless 16-way select ----
    float r =
        op == 14 ? fOr  :
        op == 15 ? fXor :
        op == 16 ? fAnd :
        op == 17 ? eq   :
        op == 18 ? ne   :
        op == 19 ? lt   :
        op == 20 ? gt   :
        op == 21 ? le   :
        op == 22 ? ge   :
        op == 23 ? fShl :
        op == 24 ? fShr :
        op == 25 ? a + b :
        op == 26 ? a - b :
        op == 27 ? a * b :
        op == 28 ? dv   :
        op == 29 ? mod  : 0.0f;
    return r;
}

__global__ __launch_bounds__(BLOCK) void c4_kernel(
        const float* __restrict__ A, const float* __restrict__ B,
        const int* __restrict__ OP, const float* __restrict__ recip_tbl,
        float* __restrict__ OUT, int n4, int n) {
    int i = blockIdx.x * BLOCK + threadIdx.x;
    if (i < n4) {
        float4 a4 = reinterpret_cast<const float4*>(A)[i];
        float4 b4 = reinterpret_cast<const float4*>(B)[i];
        int4   o4 = reinterpret_cast<const int4*>(OP)[i];
        float4 r;
        r.x = compute_one(a4.x, b4.x, o4.x, recip_tbl);
        r.y = compute_one(a4.y, b4.y, o4.y, recip_tbl);
        r.z = compute_one(a4.z, b4.z, o4.z, recip_tbl);
        r.w = compute_one(a4.w, b4.w, o4.w, recip_tbl);
        reinterpret_cast<float4*>(OUT)[i] = r;
    }
    if (i == 0) {   // scalar tail (empty when n % 4 == 0)
        for (int j = n4 * 4; j < n; ++j)
            OUT[j] = compute_one(A[j], B[j], OP[j], recip_tbl);
    }
}

extern "C" void kernel_launch(void* const* d_in, const int* in_sizes, int n_in,
                              void* d_out, int out_size, void* d_ws, size_t ws_size,
                              hipStream_t stream) {
    const float* A     = (const float*)d_in[0];
    const float* B     = (const float*)d_in[1];
    const float* recip = (const float*)d_in[3];
    const int*   OP    = (const int*)d_in[4];
    float* OUT = (float*)d_out;
    int n  = in_sizes[0];
    int n4 = n / 4;
    int blocks = (n4 + BLOCK - 1) / BLOCK;
    if (blocks < 1) blocks = 1;
    c4_kernel<<<blocks, BLOCK, 0, stream>>>(A, B, OP, recip, OUT, n4, n);
}

// Round 5
// 72.274 us; speedup vs baseline: 1.1120x; 1.0092x over previous
//
#include <hip/hip_runtime.h>

// C4Transformer: per-element opcode-routed expert compute, fully branchless.
// Inputs: a f32[N], b f32[N], log_keys f32[161], recip_values f32[161],
// opcode i32[N].  Output f32[N].
//
// R4 -> R5: identical to R4 (R4 never ran: GPU acquisition timeout).
//  - all 4 IEEE divisions -> v_rcp_f32 (1 ulp; threshold is 4.3e7)
//  - div/mod softmax window: analytic 3-term, 1 exp + 1 exp2 + 1 log2,
//    zero table loads (recip_k = 2^{-k/8} computed in-register).

static constexpr int BLOCK = 256;

__device__ __forceinline__ float rcpf(float x)  { return __builtin_amdgcn_rcpf(x); }
__device__ __forceinline__ float exp2f_(float x){ return __builtin_amdgcn_exp2f(x); }

__device__ __forceinline__ float compute_one(float a, float b, int op) {
    // ---- int-domain experts (bit-exact numpy semantics) ----
    int ai = (int)a, bi = (int)b;
    int sh = bi < 0 ? 0 : (bi > 31 ? 31 : bi);
    float fOr  = (float)(ai | bi);
    float fXor = (float)(ai ^ bi);
    float fAnd = (float)(ai & bi);
    float fShl = (float)((int)(((unsigned)ai) << sh));
    float fShr = (float)(ai >> sh);

    // ---- comparison experts: one exp covers all six ----
    // ge = (silu(t+20)-silu(t))/20, gt = (silu(t)-silu(t-20))/20, t = 20(a-b);
    // sigmoid(t+c) = 1/(1+E*e^-c) with E = e^-t.  Saturation: E=inf -> silu=0;
    // E=0 -> silu(x)=x.  lt=1-ge, le=1-gt, eq=ge*le, ne=1-eq.
    const float EM20 = 2.0611536e-9f;   // e^-20
    const float EP20 = 4.8516520e+8f;   // e^+20
    float t = 20.0f * (a - b);
    float E = __expf(-t);
    float sp = (t + 20.0f) * rcpf(1.0f + E * EM20);
    float s0 = t           * rcpf(1.0f + E);
    float sm = (t - 20.0f) * rcpf(1.0f + E * EP20);
    float ge = (sp - s0) * 0.05f;
    float gt = (s0 - sm) * 0.05f;
    float lt = 1.0f - ge;
    float le = 1.0f - gt;
    float eq = ge * le;
    float ne = 1.0f - eq;

    // ---- div/mod: analytic 3-term softmax window (1 exp + 1 exp2 + 1 log2) ----
    // b<=0 paths produce NaN/garbage and are selected away below.
    const float E625   = 1.9304541e-3f;  // e^-6.25
    const float TWO_M8 = 0.89089871814f; // 2^-1/8
    const float TWO_P8 = 1.12246204831f; // 2^+1/8
    float logb = __log2f(b);                        // NaN b<0, -inf b==0
    float fi0  = floorf(logb * 8.0f + 0.5f);
    fi0 = fminf(fmaxf(fi0, 0.0f), 160.0f);          // NaN/-inf -> 0
    float u  = logb - 0.125f * fi0;
    float r0 = exp2f_(-0.125f * fi0);
    bool  up = (u >= 0.0f);                         // NaN -> false (fine)
    float rT = r0 * (up ? TWO_M8 : TWO_P8);         // toward-side key recip
    float rA = r0 * (up ? TWO_P8 : TWO_M8);         // away-side key recip
    float wT = E625 * __expf(100.0f * fabsf(u));
    float wA = E625;
    int i0 = (int)fi0;
    int dT = up ? 1 : -1;
    int iT = i0 + dT, iA = i0 - dT;
    if (iT < 0 || iT > 160) wT = 0.0f;
    if (iA < 0 || iA > 160) wA = 0.0f;
    float recip = (r0 + wT * rT + wA * rA) * rcpf(1.0f + wT + wA);
    float dvraw = floorf(a * recip);
    float dv  = (b > 0.0f) ? dvraw : 0.0f;
    float mod = (b == 0.0f) ? 0.0f : fmaf(-dv, b, a);

    // ---- branchless 16-way select ----
    float r =
        op == 14 ? fOr  :
        op == 15 ? fXor :
        op == 16 ? fAnd :
        op == 17 ? eq   :
        op == 18 ? ne   :
        op == 19 ? lt   :
        op == 20 ? gt   :
        op == 21 ? le   :
        op == 22 ? ge   :
        op == 23 ? fShl :
        op == 24 ? fShr :
        op == 25 ? a + b :
        op == 26 ? a - b :
        op == 27 ? a * b :
        op == 28 ? dv   :
        op == 29 ? mod  : 0.0f;
    return r;
}

__global__ __launch_bounds__(BLOCK) void c4_kernel(
        const float* __restrict__ A, const float* __restrict__ B,
        const int* __restrict__ OP,
        float* __restrict__ OUT, int n4, int n) {
    int i = blockIdx.x * BLOCK + threadIdx.x;
    if (i < n4) {
        float4 a4 = reinterpret_cast<const float4*>(A)[i];
        float4 b4 = reinterpret_cast<const float4*>(B)[i];
        int4   o4 = reinterpret_cast<const int4*>(OP)[i];
        float4 r;
        r.x = compute_one(a4.x, b4.x, o4.x);
        r.y = compute_one(a4.y, b4.y, o4.y);
        r.z = compute_one(a4.z, b4.z, o4.z);
        r.w = compute_one(a4.w, b4.w, o4.w);
        reinterpret_cast<float4*>(OUT)[i] = r;
    }
    if (i == 0) {   // scalar tail (empty when n % 4 == 0)
        for (int j = n4 * 4; j < n; ++j)
            OUT[j] = compute_one(A[j], B[j], OP[j]);
    }
}

extern "C" void kernel_launch(void* const* d_in, const int* in_sizes, int n_in,
                              void* d_out, int out_size, void* d_ws, size_t ws_size,
                              hipStream_t stream) {
    const float* A  = (const float*)d_in[0];
    const float* B  = (const float*)d_in[1];
    const int*   OP = (const int*)d_in[4];
    float* OUT = (float*)d_out;
    int n  = in_sizes[0];
    int n4 = n / 4;
    int blocks = (n4 + BLOCK - 1) / BLOCK;
    if (blocks < 1) blocks = 1;
    c4_kernel<<<blocks, BLOCK, 0, stream>>>(A, B, OP, OUT, n4, n);
}